// Round 5
// baseline (309.950 us; speedup 1.0000x reference)
//
#include <hip/hip_runtime.h>
#include <cstdint>

#define B_    64
#define NV_   6890
#define NF_   13776
#define NHD_  20000
#define NP_   24
#define NCH   216           // ceil(6890/32) k-chunks of 32
#define KSPL  4             // split-K across waves in a block
#define CPW   54            // chunks per wave (216/4)

// ---------------- workspace layout (bytes) ----------------
#define OFF_PPV   0u        // ppv [64][24] f32   6144   (zeroed)
#define OFF_RED   6144u     // red [64][6]  f32   1536   (zeroed)
#define ZERO_BYTES 7680u
#define OFF_VC    7680u     // Vc [216][12][64][8] bf16 = 2,654,208 B (fully rewritten)

typedef __attribute__((ext_vector_type(8))) __bf16 bf16x8;
typedef __attribute__((ext_vector_type(8))) unsigned short u16x8;
typedef __attribute__((ext_vector_type(4))) float f32x4;

__device__ __forceinline__ unsigned short f2bf(float f) {
    unsigned u = __float_as_uint(f);
    u = (u + 0x7fffu + ((u >> 16) & 1u)) >> 16;   // RNE (no NaNs here)
    return (unsigned short)u;
}

// ---------------- K0v: pack V into MFMA-fragment order (unchanged layout) ----------------
// Vc[((c*12 + t)*64 + lane)*8 + j] = V_bf16[bd = t*16 + (lane&15)][k = c*32 + (lane>>4)*8 + j]
__global__ __launch_bounds__(256) void k0v_pack(const float* __restrict__ verts,
                                                unsigned short* __restrict__ Vc) {
    int idx = blockIdx.x * 256 + threadIdx.x;       // 216*12*512 = 1,327,104 total
    int j    = idx & 7;
    int lane = (idx >> 3) & 63;
    int ct   = idx >> 9;                            // c*12 + t
    int t    = ct % 12;
    int c    = ct / 12;
    int lm   = lane & 15;
    int kk   = (lane >> 4) * 8 + j;
    int bd   = t * 16 + lm;
    int d    = bd >> 6, b = bd & 63;
    int k    = c * 32 + kk;
    float v  = (k < NV_) ? verts[((size_t)b * NV_ + k) * 3 + d] : 0.f;
    Vc[idx] = f2bf(v);
}

// ---------------- K1: per-part volumes ----------------
__global__ __launch_bounds__(256) void k1_vol(const float* __restrict__ verts,
                                              const int* __restrict__ faces,
                                              const int* __restrict__ face_part,
                                              float* __restrict__ ppv) {
    __shared__ float bins[NP_];
    int b = blockIdx.y;
    int f = blockIdx.x * 256 + threadIdx.x;
    if (threadIdx.x < NP_) bins[threadIdx.x] = 0.f;
    __syncthreads();
    if (f < NF_) {
        int i0 = faces[3 * f], i1 = faces[3 * f + 1], i2 = faces[3 * f + 2];
        const float* vb = verts + (size_t)b * NV_ * 3;
        float ax = vb[3 * i0], ay = vb[3 * i0 + 1], az = vb[3 * i0 + 2];
        float bx = vb[3 * i1], by = vb[3 * i1 + 1], bz = vb[3 * i1 + 2];
        float cx = vb[3 * i2], cy = vb[3 * i2 + 1], cz = vb[3 * i2 + 2];
        float crx = by * cz - bz * cy;
        float cry = bz * cx - bx * cz;
        float crz = bx * cy - by * cx;
        float vol = fabsf(ax * crx + ay * cry + az * crz) * (1.0f / 6.0f);
        atomicAdd(&bins[face_part[f]], vol);
    }
    __syncthreads();
    if (threadIdx.x < NP_) atomicAdd(&ppv[b * NP_ + threadIdx.x], bins[threadIdx.x]);
}

// ---------------- KF: 32 rows/block, 4-wave split-K, sched_barrier-clustered loads --------
#define ACCP 193            // padded LDS stride
__global__ __launch_bounds__(256) void kf_fused(const float* __restrict__ Hm,
                                                const unsigned short* __restrict__ Vc,
                                                const int* __restrict__ vert_fid,
                                                const int* __restrict__ face_part,
                                                const float* __restrict__ ppv,
                                                float* __restrict__ red) {
    __shared__ float accs[32 * ACCP];   // 24,704 B
    __shared__ float reds[B_ * 6];
    const int tid  = threadIdx.x;
    const int lane = tid & 63;
    const int s    = tid >> 6;          // wave id = K-split id
    const int lm   = lane & 15;
    const int kg   = lane >> 4;
    const int n0   = blockIdx.x * 32;
    const float* Arow0 = Hm + (size_t)(n0 + lm) * NV_;
    const float* Arow1 = Hm + (size_t)(n0 + 16 + lm) * NV_;
    const int cs = s * CPW, ce = cs + CPW;
    const int ce_main = (s == KSPL - 1) ? (NCH - 1) : ce;   // peel partial chunk 215

    f32x4 acc0[12], acc1[12];
#pragma unroll
    for (int t = 0; t < 12; ++t) {
        acc0[t] = (f32x4){0.f, 0.f, 0.f, 0.f};
        acc1[t] = (f32x4){0.f, 0.f, 0.f, 0.f};
    }

    float2 a[4], b[4];
    {   // prologue: load A chunk cs (always a full chunk)
        int k0 = cs * 32 + kg * 8;
#pragma unroll
        for (int j = 0; j < 4; ++j) {
            a[j] = *reinterpret_cast<const float2*>(Arow0 + k0 + 2 * j);
            b[j] = *reinterpret_cast<const float2*>(Arow1 + k0 + 2 * j);
        }
    }

#pragma unroll 1
    for (int c = cs; c < ce_main; ++c) {
        // ---- 12 B-tile fragment loads (1KB coalesced each, L2/L3-resident Vc) ----
        const u16x8* Bp = reinterpret_cast<const u16x8*>(Vc) + (size_t)c * 768 + lane;
        u16x8 Bu[12];
#pragma unroll
        for (int t = 0; t < 12; ++t) Bu[t] = Bp[t * 64];
        __builtin_amdgcn_sched_barrier(0);   // pin: all 12 B loads issued above this point

        // ---- A prefetch for next chunk (clamped, branchless; discarded on last iter) ----
        const int cpf = (c + 1 < ce_main) ? (c + 1) : cs;
        const int k0n = cpf * 32 + kg * 8;
        float2 na[4], nb[4];
#pragma unroll
        for (int j = 0; j < 4; ++j) {
            na[j] = *reinterpret_cast<const float2*>(Arow0 + k0n + 2 * j);
            nb[j] = *reinterpret_cast<const float2*>(Arow1 + k0n + 2 * j);
        }
        __builtin_amdgcn_sched_barrier(0);   // pin: A prefetch issued before compute

        // ---- convert current A to bf16 frags (native cvt, RNE) ----
        bf16x8 Af0, Af1;
#pragma unroll
        for (int j = 0; j < 4; ++j) {
            Af0[2 * j]     = (__bf16)a[j].x;
            Af0[2 * j + 1] = (__bf16)a[j].y;
            Af1[2 * j]     = (__bf16)b[j].x;
            Af1[2 * j + 1] = (__bf16)b[j].y;
        }
#pragma unroll
        for (int t = 0; t < 12; ++t)
            acc0[t] = __builtin_amdgcn_mfma_f32_16x16x32_bf16(
                Af0, __builtin_bit_cast(bf16x8, Bu[t]), acc0[t], 0, 0, 0);
#pragma unroll
        for (int t = 0; t < 12; ++t)
            acc1[t] = __builtin_amdgcn_mfma_f32_16x16x32_bf16(
                Af1, __builtin_bit_cast(bf16x8, Bu[t]), acc1[t], 0, 0, 0);
#pragma unroll
        for (int j = 0; j < 4; ++j) { a[j] = na[j]; b[j] = nb[j]; }
    }

    // ---- peeled tail: wave 3 handles partial chunk 215 (k 6880..6889 valid) ----
    if (ce > ce_main) {
        const int c = NCH - 1;
        const u16x8* Bp = reinterpret_cast<const u16x8*>(Vc) + (size_t)c * 768 + lane;
        u16x8 Bu[12];
#pragma unroll
        for (int t = 0; t < 12; ++t) Bu[t] = Bp[t * 64];
        const int k0 = c * 32 + kg * 8;
        bf16x8 Af0, Af1;
#pragma unroll
        for (int j = 0; j < 8; ++j) {
            int k = k0 + j;
            float fa = (k < NV_) ? Arow0[k] : 0.f;
            float fb = (k < NV_) ? Arow1[k] : 0.f;
            Af0[j] = (__bf16)fa;
            Af1[j] = (__bf16)fb;
        }
#pragma unroll
        for (int t = 0; t < 12; ++t)
            acc0[t] = __builtin_amdgcn_mfma_f32_16x16x32_bf16(
                Af0, __builtin_bit_cast(bf16x8, Bu[t]), acc0[t], 0, 0, 0);
#pragma unroll
        for (int t = 0; t < 12; ++t)
            acc1[t] = __builtin_amdgcn_mfma_f32_16x16x32_bf16(
                Af1, __builtin_bit_cast(bf16x8, Bu[t]), acc1[t], 0, 0, 0);
    }

    // ---- split-K reduction in LDS ----
    for (int i = tid; i < 32 * ACCP; i += 256) accs[i] = 0.f;
    for (int i = tid; i < B_ * 6; i += 256) reds[i] = 0.f;
    __syncthreads();
    // acc0[t][r] = C[row = kg*4 + r][bd = t*16 + lm], acc1 rows +16 (verified mapping)
#pragma unroll
    for (int t = 0; t < 12; ++t)
#pragma unroll
        for (int r = 0; r < 4; ++r) {
            atomicAdd(&accs[(kg * 4 + r) * ACCP + t * 16 + lm], acc0[t][r]);
            atomicAdd(&accs[(16 + kg * 4 + r) * ACCP + t * 16 + lm], acc1[t][r]);
        }
    __syncthreads();

    // ---- epilogue: pw from y-plane, weight x/z, per-b reduce ----
    {
        int bb = tid & 63;
        int r0 = tid >> 6;              // 0..3
        float scx = 0.f, scz = 0.f, smx = 0.f, smz = 0.f, ssp = 0.f, ssw = 0.f;
#pragma unroll
        for (int q = 0; q < 8; ++q) {
            int row = q * 4 + r0;       // 0..31
            int n = n0 + row;
            float x = accs[row * ACCP + bb];
            float h = accs[row * ACCP + 64 + bb];
            float z = accs[row * ACCP + 128 + bb];
            float pwv = (h < 0.f) ? (1.f - 100.f * h) : expf(-10.f * h);
            int part = face_part[vert_fid[n]];
            float w = ppv[bb * NP_ + part];
            scx += pwv * x; scz += pwv * z;
            smx += w * x;   smz += w * z;
            ssp += pwv;     ssw += w;
        }
        atomicAdd(&reds[bb * 6 + 0], scx);
        atomicAdd(&reds[bb * 6 + 1], scz);
        atomicAdd(&reds[bb * 6 + 2], smx);
        atomicAdd(&reds[bb * 6 + 3], smz);
        atomicAdd(&reds[bb * 6 + 4], ssp);
        atomicAdd(&reds[bb * 6 + 5], ssw);
    }
    __syncthreads();
    for (int i = tid; i < B_ * 6; i += 256) atomicAdd(&red[i], reds[i]);
}

// ---------------- K5: finalize ----------------
__global__ __launch_bounds__(64) void k5_final(const float* __restrict__ red,
                                               float* __restrict__ out) {
    int b = threadIdx.x;
    if (b < B_) {
        float sp   = red[b * 6 + 4] + 1e-6f;
        float sw   = red[b * 6 + 5];
        float copx = red[b * 6 + 0] / sp;
        float copz = red[b * 6 + 1] / sp;
        float comx = red[b * 6 + 2] / sw;
        float comz = red[b * 6 + 3] / sw;
        float dx = comx - copx, dz = comz - copz;
        out[b] = sqrtf(dx * dx + dz * dz);
    }
}

extern "C" void kernel_launch(void* const* d_in, const int* in_sizes, int n_in,
                              void* d_out, int out_size, void* d_ws, size_t ws_size,
                              hipStream_t stream) {
    const float* verts     = (const float*)d_in[0];
    const float* Hm        = (const float*)d_in[1];
    const int*   faces     = (const int*)d_in[2];
    const int*   vert_fid  = (const int*)d_in[3];
    const int*   face_part = (const int*)d_in[4];
    char* ws = (char*)d_ws;
    float*          ppv = (float*)(ws + OFF_PPV);
    float*          red = (float*)(ws + OFF_RED);
    unsigned short* Vc  = (unsigned short*)(ws + OFF_VC);
    float* out = (float*)d_out;

    hipMemsetAsync(d_ws, 0, ZERO_BYTES, stream);
    hipLaunchKernelGGL(k0v_pack, dim3((NCH * 12 * 512) / 256), dim3(256), 0, stream, verts, Vc);
    hipLaunchKernelGGL(k1_vol, dim3(54, 64), dim3(256), 0, stream, verts, faces, face_part, ppv);
    hipLaunchKernelGGL(kf_fused, dim3(NHD_ / 32), dim3(256), 0, stream,
                       Hm, Vc, vert_fid, face_part, ppv, red);
    hipLaunchKernelGGL(k5_final, dim3(1), dim3(64), 0, stream, red, out);
}